// Round 2
// baseline (246.178 us; speedup 1.0000x reference)
//
#include <hip/hip_runtime.h>

#define B_    64
#define C_    2048
#define HW_   288
#define EPS_  0.07f
#define TINY_ 1e-8f
#define NCH_  64
#define CPC_  (C_ / NCH_)   // 32 rows per chunk
#define NGRP_ 16            // chunk-groups per batch (4 chunks / group = 1 block)

__device__ __forceinline__ float comp(const float4 v, int i) {
  return i == 0 ? v.x : i == 1 ? v.y : i == 2 ? v.z : v.w;
}

__device__ __forceinline__ void acc3(const float4 v, float a0, float a1,
                                     float* ssq, float* sd0, float* sd1) {
  ssq[0] += v.x * v.x; ssq[1] += v.y * v.y; ssq[2] += v.z * v.z; ssq[3] += v.w * v.w;
  sd0[0] += v.x * a0;  sd0[1] += v.y * a0;  sd0[2] += v.z * a0;  sd0[3] += v.w * a0;
  sd1[0] += v.x * a1;  sd1[1] += v.y * a1;  sd1[2] += v.z * a1;  sd1[3] += v.w * a1;
}

// ---------------------------------------------------------------------------
// Kernel 1 (unchanged from R1): per-token partial sums, one C-chunk per WAVE,
// x-rows AND anchors double-buffered in 4-row groups; 4 waves of a block
// combine their chunk partials in LDS before writing one group-partial.
// grid = B*NCH/4 = 1024 blocks, 256 threads.
// part layout: [B][NGRP_][3 planes][288] (3.54 MB).
// ---------------------------------------------------------------------------
__global__ __launch_bounds__(256) void k1_partials(
    const float* __restrict__ x, const float* __restrict__ anchors,
    float* __restrict__ part) {
  __shared__ float4 lds[4][3][72];   // [wave][plane][float4 token-quad] = 13.8 KB

  int bi = blockIdx.x;
  int b  = bi >> 4;                // NGRP_ = 16 chunk-groups per b
  int cg = bi & 15;
  int t = threadIdx.x, lane = t & 63, wid = t >> 6;
  int ch = cg * 4 + wid;
  int c0 = ch * CPC_;
  const float* xb = x + ((size_t)b * C_ + c0) * HW_;
  const float4* a0v = (const float4*)(anchors + c0);        // c0 % 32 == 0
  const float4* a1v = (const float4*)(anchors + C_ + c0);

  float ssq[4] = {0,0,0,0}, sd0[4] = {0,0,0,0}, sd1[4] = {0,0,0,0};

  float4 xbuf[4], abuf0, abuf1;
#pragma unroll
  for (int j = 0; j < 4; ++j)
    xbuf[j] = ((const float4*)(xb + (size_t)j * HW_))[lane];
  abuf0 = a0v[0];
  abuf1 = a1v[0];

#pragma unroll 1
  for (int r = 0; r < CPC_; r += 4) {
    float4 xcur[4], ac0 = abuf0, ac1 = abuf1;
#pragma unroll
    for (int j = 0; j < 4; ++j) xcur[j] = xbuf[j];
    if (r + 4 < CPC_) {
#pragma unroll
      for (int j = 0; j < 4; ++j)
        xbuf[j] = ((const float4*)(xb + (size_t)(r + 4 + j) * HW_))[lane];
      abuf0 = a0v[(r >> 2) + 1];
      abuf1 = a1v[(r >> 2) + 1];
    }
#pragma unroll
    for (int j = 0; j < 4; ++j)
      acc3(xcur[j], comp(ac0, j), comp(ac1, j), ssq, sd0, sd1);
  }

  // tail: h float4s 64..71 (one 128B line per row); rows k*8+(lane>>3)
  int rg = lane >> 3, q = lane & 7;
  float4 tv[4];
  float ta0[4], ta1[4];
#pragma unroll
  for (int k = 0; k < CPC_ / 8; ++k) {
    int r = k * 8 + rg;
    tv[k]  = ((const float4*)(xb + (size_t)r * HW_))[64 + q];
    ta0[k] = anchors[c0 + r];
    ta1[k] = anchors[C_ + c0 + r];
  }
  float tsq[4] = {0,0,0,0}, td0[4] = {0,0,0,0}, td1[4] = {0,0,0,0};
#pragma unroll
  for (int k = 0; k < CPC_ / 8; ++k)
    acc3(tv[k], ta0[k], ta1[k], tsq, td0, td1);
#pragma unroll
  for (int off = 8; off < 64; off <<= 1) {
#pragma unroll
    for (int j = 0; j < 4; ++j) {
      tsq[j] += __shfl_xor(tsq[j], off);
      td0[j] += __shfl_xor(td0[j], off);
      td1[j] += __shfl_xor(td1[j], off);
    }
  }

  // Stage this wave's 3x288-float chunk partials into LDS.
  lds[wid][0][lane] = make_float4(ssq[0], ssq[1], ssq[2], ssq[3]);
  lds[wid][1][lane] = make_float4(sd0[0], sd0[1], sd0[2], sd0[3]);
  lds[wid][2][lane] = make_float4(sd1[0], sd1[1], sd1[2], sd1[3]);
  if (lane < 8) {
    lds[wid][0][64 + lane] = make_float4(tsq[0], tsq[1], tsq[2], tsq[3]);
    lds[wid][1][64 + lane] = make_float4(td0[0], td0[1], td0[2], td0[3]);
    lds[wid][2][64 + lane] = make_float4(td1[0], td1[1], td1[2], td1[3]);
  }
  __syncthreads();

  // Combine the 4 waves' chunks and write ONE group-partial (3*288 floats).
  if (t < 216) {
    int p = t / 72, i = t - p * 72;
    float4 s0 = lds[0][p][i], s1 = lds[1][p][i];
    float4 s2 = lds[2][p][i], s3 = lds[3][p][i];
    float4 s = make_float4(s0.x + s1.x + s2.x + s3.x,
                           s0.y + s1.y + s2.y + s3.y,
                           s0.z + s1.z + s2.z + s3.z,
                           s0.w + s1.w + s2.w + s3.w);
    ((float4*)(part + ((size_t)(b * NGRP_ + cg) * 3 + p) * HW_))[i] = s;
  }
}

// Block-wide 2-value sum reduction for 256 threads (4 full waves).
__device__ __forceinline__ void block_reduce2(
    float& p0, float& p1, volatile float* red0, volatile float* red1, int t) {
  int lane = t & 63, wid = t >> 6;
#pragma unroll
  for (int off = 32; off >= 1; off >>= 1) {
    p0 += __shfl_down(p0, off);
    p1 += __shfl_down(p1, off);
  }
  __syncthreads();
  if (lane == 0) { red0[wid] = p0; red1[wid] = p1; }
  __syncthreads();
  p0 = red0[0] + red0[1] + red0[2] + red0[3];
  p1 = red1[0] + red1[1] + red1[2] + red1[3];
}

// ---------------------------------------------------------------------------
// Kernel 2+3 FUSED: every block redundantly collapses its batch's 16 group-
// partials (55 KB, L2/L3-resident) and runs the 7-iteration Sinkhorn for its
// batch (parallel across all 1024 blocks — replaces the serial 64-block k2),
// then does the masked pooling on its 128-channel segment. m -> LDS -> regs;
// invden computed locally (no ws round-trip). seg==0 blocks write out_m.
// Token split for sinkhorn on 256 threads: thread t owns token t, and
// threads t<32 additionally own token 256+t.
// grid = B*16 = 1024 blocks, 256 threads.
// ---------------------------------------------------------------------------
__global__ __launch_bounds__(256) void k23_fused(
    const float* __restrict__ x, const float* __restrict__ part,
    const float* __restrict__ anchors, float* __restrict__ out,
    float* __restrict__ out_m) {
  int bi = blockIdx.x;
  int b = bi >> 4, seg = bi & 15;
  int t = threadIdx.x, oct = t & 7, rl = t >> 3;   // rl = 0..31

  __shared__ float red0[4], red1[4];
  __shared__ float sm0[HW_], sm1[HW_];

  // ---- collapse group-partials for this block's tokens (independent loads
  //      issued first so they're in flight during the anchor-norm reduce) ----
  const float* p = part + (size_t)b * NGRP_ * 3 * HW_;
  float ssqa = 0.f, d0a = 0.f, d1a = 0.f;
#pragma unroll
  for (int g = 0; g < NGRP_; ++g) {
    const float* q = p + (size_t)g * 3 * HW_ + t;
    ssqa += q[0];
    d0a  += q[HW_];
    d1a  += q[2 * HW_];
  }
  float ssqb = 0.f, d0b = 0.f, d1b = 0.f;
  if (t < 32) {
#pragma unroll
    for (int g = 0; g < NGRP_; ++g) {
      const float* q = p + (size_t)g * 3 * HW_ + 256 + t;
      ssqb += q[0];
      d0b  += q[HW_];
      d1b  += q[2 * HW_];
    }
  }

  // ---- anchor norms (redundant per block; 2048*2 floats, L2-hot) ----
  float a0 = 0.f, a1 = 0.f;
  for (int c = t; c < C_; c += 256) {
    float q0 = anchors[c], q1 = anchors[C_ + c];
    a0 += q0 * q0; a1 += q1 * q1;
  }
  block_reduce2(a0, a1, red0, red1, t);
  float ian0 = 1.0f / fmaxf(sqrtf(a0), 1e-12f);
  float ian1 = 1.0f / fmaxf(sqrtf(a1), 1e-12f);

  // ---- K matrix entries ----
  float ixna = 1.0f / fmaxf(sqrtf(ssqa), 1e-12f);
  float K0a = expf((d0a * ixna * ian0 - 1.0f) / EPS_) + TINY_;
  float K1a = expf((d1a * ixna * ian1 - 1.0f) / EPS_) + TINY_;
  float K0b = 0.f, K1b = 0.f;
  if (t < 32) {
    float ixnb = 1.0f / fmaxf(sqrtf(ssqb), 1e-12f);
    K0b = expf((d0b * ixnb * ian0 - 1.0f) / EPS_) + TINY_;
    K1b = expf((d1b * ixnb * ian1 - 1.0f) / EPS_) + TINY_;
  }

  // ---- 7 Sinkhorn iterations (per-block, redundant across segs) ----
  float v0 = 1.f, v1 = 1.f, ua = 0.f, ub = 0.f;
  for (int it = 0; it < 7; ++it) {
    ua = (1.0f / (float)HW_) / (K0a * v0 + K1a * v1 + TINY_);
    ub = (t < 32) ? (1.0f / (float)HW_) / (K0b * v0 + K1b * v1 + TINY_) : 0.f;
    float p0 = K0a * ua + K0b * ub;
    float p1 = K1a * ua + K1b * ub;
    block_reduce2(p0, p1, red0, red1, t);
    v0 = 0.5f / (p0 + TINY_);
    v1 = 0.5f / (p1 + TINY_);
  }

  // ---- masks ----
  float m0a = K0a * ua * v0 * (float)HW_;
  float m1a = K1a * ua * v1 * (float)HW_;
  float m0b = 0.f, m1b = 0.f;
  sm0[t] = m0a; sm1[t] = m1a;
  if (t < 32) {
    m0b = K0b * ub * v0 * (float)HW_;
    m1b = K1b * ub * v1 * (float)HW_;
    sm0[256 + t] = m0b; sm1[256 + t] = m1b;
  }
  float q0 = m0a + m0b, q1 = m1a + m1b;
  block_reduce2(q0, q1, red0, red1, t);   // barriers also publish sm0/sm1
  float inv0 = 1.0f / (q0 + 1e-6f);
  float inv1 = 1.0f / (q1 + 1e-6f);

  if (seg == 0) {
    out_m[(b * 2 + 0) * HW_ + t] = m0a;
    out_m[(b * 2 + 1) * HW_ + t] = m1a;
    if (t < 32) {
      out_m[(b * 2 + 0) * HW_ + 256 + t] = m0b;
      out_m[(b * 2 + 1) * HW_ + 256 + t] = m1b;
    }
  }

  // ---- masked pooling (R5-proven octant mapping) ----
  float4 w0[9], w1[9];
#pragma unroll
  for (int j = 0; j < 9; ++j) {
    w0[j] = ((const float4*)sm0)[oct + 8 * j];
    w1[j] = ((const float4*)sm1)[oct + 8 * j];
  }

  int cbase = seg * 128;
#pragma unroll 1
  for (int g = 0; g < 4; ++g) {
    int c = cbase + g * 32 + rl;
    const float4* xr = (const float4*)(x + ((size_t)b * C_ + c) * HW_);
    float4 xa[9];
#pragma unroll
    for (int j = 0; j < 9; ++j) xa[j] = xr[oct + 8 * j];
    float a0s = 0.f, a1s = 0.f;
#pragma unroll
    for (int j = 0; j < 9; ++j) {
      a0s += xa[j].x * w0[j].x + xa[j].y * w0[j].y + xa[j].z * w0[j].z + xa[j].w * w0[j].w;
      a1s += xa[j].x * w1[j].x + xa[j].y * w1[j].y + xa[j].z * w1[j].z + xa[j].w * w1[j].w;
    }
#pragma unroll
    for (int off = 4; off >= 1; off >>= 1) {
      a0s += __shfl_xor(a0s, off);
      a1s += __shfl_xor(a1s, off);
    }
    if (oct == 0) {
      out[(size_t)b * C_ + c] = a0s * inv0;
      out[(size_t)B_ * C_ + (size_t)b * C_ + c] = a1s * inv1;
    }
  }
}

extern "C" void kernel_launch(void* const* d_in, const int* in_sizes, int n_in,
                              void* d_out, int out_size, void* d_ws, size_t ws_size,
                              hipStream_t stream) {
  const float* x       = (const float*)d_in[0];
  const float* anchors = (const float*)d_in[1];
  float* out = (float*)d_out;

  // ws layout: part[B*NGRP_*3*288]  (~3.54 MB)
  float* part = (float*)d_ws;

  float* out_m = out + 2 * B_ * C_;  // m region of d_out (B,2,H,W)

  k1_partials<<<B_ * (NCH_ / 4), 256, 0, stream>>>(x, anchors, part);
  k23_fused<<<B_ * 16, 256, 0, stream>>>(x, part, anchors, out, out_m);
}